// Round 1
// 254.121 us; speedup vs baseline: 1.0225x; 1.0225x over previous
//
#include <hip/hip_runtime.h>
#include <hip/hip_bf16.h>

typedef unsigned short ushort_t;
typedef __attribute__((ext_vector_type(8))) short bf16x8;
typedef __attribute__((ext_vector_type(4))) float f32x4;

#define B_SZ 4096
#define N_SZ 8
#define D_SZ 256
#define FF_SZ 2048
#define M_SZ (B_SZ * N_SZ)   // 32768
#define WELEM (D_SZ * D_SZ * N_SZ)  // 524288

__device__ inline float b2f(ushort_t u) {
    union { unsigned int i; float f; } t; t.i = ((unsigned int)u) << 16; return t.f;
}
__device__ inline ushort_t f2b(float f) {
    union { unsigned int i; float f; } t; t.f = f;
    unsigned int i = t.i;
    unsigned int r = (i + 0x7fffu + ((i >> 16) & 1u)) >> 16;
    return (ushort_t)r;
}

// async global->LDS, 16B per lane; LDS dest must be wave-uniform base + lane*16
__device__ inline void gl2lds16(const ushort_t* g, ushort_t* l) {
    __builtin_amdgcn_global_load_lds((const __attribute__((address_space(1))) void*)g,
                                     (__attribute__((address_space(3))) void*)l, 16, 0, 0);
}

// ---------------- convert/repack all weights f32 -> bf16 (unchanged)
__global__ __launch_bounds__(256) void convert_weights(const float* __restrict__ w_in,
                                                       const float* __restrict__ w_out,
                                                       const float* __restrict__ W1,
                                                       const float* __restrict__ W2,
                                                       ushort_t* __restrict__ bt_in,
                                                       ushort_t* __restrict__ bt_out,
                                                       ushort_t* __restrict__ W1b,
                                                       ushort_t* __restrict__ W2b) {
    __shared__ float tile[64][65];
    const int bid = blockIdx.x;
    const int t = threadIdx.x;
    if (bid < 256) {
        const float* w = (bid < 128) ? w_in : w_out;
        ushort_t* bt = (bid < 128) ? bt_in : bt_out;
        const int id = bid & 127;
        const int d10 = (id >> 5) * 64;
        const int j0  = (id & 31) * 64;
#pragma unroll
        for (int it = 0; it < 16; ++it) {
            const int d1l = it * 4 + (t >> 6);
            const int jl = t & 63;
            tile[d1l][jl] = w[(size_t)(d10 + d1l) * 2048 + j0 + jl];
        }
        __syncthreads();
#pragma unroll
        for (int it = 0; it < 16; ++it) {
            const int jl = it * 4 + (t >> 6);
            const int d1l = t & 63;
            const int j = j0 + jl;
            bt[(size_t)(j >> 3) * 2048 + (j & 7) * 256 + d10 + d1l] = f2b(tile[d1l][jl]);
        }
    } else {
        const int id = bid - 256;
        const float* w = (id < 256) ? W1 : W2;
        ushort_t* o = (id < 256) ? W1b : W2b;
        const size_t base = (size_t)(id & 255) * 2048 + t * 8;
        const float4 a = *(const float4*)&w[base];
        const float4 b = *(const float4*)&w[base + 4];
        *(ushort4*)&o[base]     = make_ushort4(f2b(a.x), f2b(a.y), f2b(a.z), f2b(a.w));
        *(ushort4*)&o[base + 4] = make_ushort4(f2b(b.x), f2b(b.y), f2b(b.z), f2b(b.w));
    }
}

// ---------------- LN1: one WAVE per row of 256 (unchanged)
__global__ __launch_bounds__(256) void ln_fast(const float* __restrict__ xin,
                                               const float* __restrict__ gam,
                                               const float* __restrict__ bet,
                                               ushort_t* __restrict__ out) {
    const int wave = threadIdx.x >> 6;
    const int lane = threadIdx.x & 63;
    const size_t row = (size_t)blockIdx.x * 4 + wave;
    const float4 v = *(const float4*)&xin[row * 256 + lane * 4];
    float s = v.x + v.y + v.z + v.w;
    float q = v.x * v.x + v.y * v.y + v.z * v.z + v.w * v.w;
#pragma unroll
    for (int off = 1; off < 64; off <<= 1) {
        s += __shfl_xor(s, off, 64);
        q += __shfl_xor(q, off, 64);
    }
    const float mu = s * (1.0f / 256.0f);
    const float var = q * (1.0f / 256.0f) - mu * mu;
    const float rs = rsqrtf(var + 1e-5f);
    const float4 g = *(const float4*)&gam[lane * 4];
    const float4 b = *(const float4*)&bet[lane * 4];
    ushort4 o;
    o.x = f2b((v.x - mu) * rs * g.x + b.x);
    o.y = f2b((v.y - mu) * rs * g.y + b.y);
    o.z = f2b((v.z - mu) * rs * g.z + b.z);
    o.w = f2b((v.w - mu) * rs * g.w + b.w);
    *(ushort4*)&out[row * 256 + lane * 4] = o;
}

// ---------------- TT gemm + fused LN2: R10 pipelined staging.
// Double-buffered As/Bs; stage(kt+1) is issued right after the barrier, so the
// vmcnt(0) drain inside the NEXT __syncthreads waits on loads that have had the
// whole MFMA phase of tile kt to complete. Staging always targets the opposite
// parity buffer from the one being computed -> every LDS producer/consumer pair
// remains separated by >=1 barrier (same invariant as R9, fewer barriers).
__global__ __launch_bounds__(512) void tt_ln2(const ushort_t* __restrict__ A,
                                              const ushort_t* __restrict__ Bt0,
                                              const ushort_t* __restrict__ Bt1,
                                              const float* __restrict__ g2,
                                              const float* __restrict__ be2,
                                              const float* __restrict__ entf,
                                              ushort_t* __restrict__ yn,
                                              ushort_t* __restrict__ xb) {
    __shared__ __attribute__((aligned(16))) ushort_t As[2][128 * 64];   // 32 KB
    __shared__ __attribute__((aligned(16))) ushort_t Bs[2][256 * 64];   // 64 KB
    __shared__ float red_s[128 * 4];
    __shared__ float red_q[128 * 4];

    const int t = threadIdx.x;
    const int m0 = blockIdx.x * 128;
    const int lane = t & 63;
    const int wave = t >> 6;
    const int wr = wave & 1, wc = wave >> 1;
    const int l16 = lane & 15, quad = lane >> 4;
    const int tr = t >> 3;
    const int csw = (((t & 7) ^ (tr & 7)) << 3);

    const ushort_t* Bt = (m0 >= M_SZ / 2) ? Bt1 : Bt0;

    f32x4 acc[4][4];
#pragma unroll
    for (int i = 0; i < 4; i++)
#pragma unroll
        for (int j = 0; j < 4; j++) acc[i][j] = (f32x4)(0.0f);

    auto stage = [&](int kt) {
        ushort_t* a = As[kt & 1];
        ushort_t* b = Bs[kt & 1];
        const int kg = kt * 64;
#pragma unroll
        for (int p = 0; p < 2; ++p) {
            const int mrow = m0 + p * 64 + tr;
            const int kcol = kg + csw;
            const int s = kcol >> 8;
            const ushort_t* gA = A + (size_t)((mrow & ~7) + (((mrow & 7) - s) & 7)) * 256 + (kcol & 255);
            gl2lds16(gA, a + p * 4096 + t * 8);
        }
#pragma unroll
        for (int p = 0; p < 4; ++p) {
            gl2lds16(Bt + (size_t)(p * 64 + tr) * 2048 + kg + csw, b + p * 4096 + t * 8);
        }
    };

    stage(0);
#pragma unroll 2
    for (int kt = 0; kt < 32; ++kt) {
        __syncthreads();            // drains stage(kt); releases buffers read at kt-1
        if (kt < 31) stage(kt + 1); // DMA overlaps the MFMAs below
        const ushort_t* a = As[kt & 1];
        const ushort_t* b = Bs[kt & 1];
#pragma unroll
        for (int kk = 0; kk < 2; ++kk) {
            const int ac = ((((kk << 2) | quad) ^ (l16 & 7)) << 3);
            bf16x8 af[4], bfv[4];
#pragma unroll
            for (int i = 0; i < 4; i++) af[i]  = *(const bf16x8*)&a[(wr * 64 + i * 16 + l16) * 64 + ac];
#pragma unroll
            for (int j = 0; j < 4; j++) bfv[j] = *(const bf16x8*)&b[(wc * 64 + j * 16 + l16) * 64 + ac];
#pragma unroll
            for (int i = 0; i < 4; i++)
#pragma unroll
                for (int j = 0; j < 4; j++)
                    acc[i][j] = __builtin_amdgcn_mfma_f32_16x16x32_bf16(af[i], bfv[j], acc[i][j], 0, 0, 0);
        }
    }

    int c[4];
#pragma unroll
    for (int j = 0; j < 4; j++) c[j] = wc * 64 + j * 16 + l16;
#pragma unroll
    for (int i = 0; i < 4; i++) {
#pragma unroll
        for (int r = 0; r < 4; r++) {
            const int rl = wr * 64 + i * 16 + quad * 4 + r;
            const size_t grow = (size_t)(m0 + rl) * 256;
            float s = 0.0f, q = 0.0f;
#pragma unroll
            for (int j = 0; j < 4; j++) {
                float v = acc[i][j][r] + entf[grow + c[j]];
                acc[i][j][r] = v;
                s += v;
                q += v * v;
            }
#pragma unroll
            for (int off = 1; off < 16; off <<= 1) {
                s += __shfl_xor(s, off, 64);
                q += __shfl_xor(q, off, 64);
            }
            if (l16 == 0) { red_s[rl * 4 + wc] = s; red_q[rl * 4 + wc] = q; }
        }
    }
    __syncthreads();
#pragma unroll
    for (int i = 0; i < 4; i++) {
#pragma unroll
        for (int r = 0; r < 4; r++) {
            const int rl = wr * 64 + i * 16 + quad * 4 + r;
            const size_t grow = (size_t)(m0 + rl) * 256;
            const float4 ss = *(const float4*)&red_s[rl * 4];
            const float4 qq = *(const float4*)&red_q[rl * 4];
            const float S = ss.x + ss.y + ss.z + ss.w;
            const float Q = qq.x + qq.y + qq.z + qq.w;
            const float mu = S * (1.0f / 256.0f);
            const float var = Q * (1.0f / 256.0f) - mu * mu;
            const float rs = rsqrtf(var + 1e-5f);
#pragma unroll
            for (int j = 0; j < 4; j++) {
                const float v = acc[i][j][r];
                yn[grow + c[j]] = f2b((v - mu) * rs * g2[c[j]] + be2[c[j]]);
                xb[grow + c[j]] = f2b(v);
            }
        }
    }
}

// ---------------- fused FF1+FF2: R10 pipelined staging, one barrier per K-tile.
// Unit stream per c-chunk: G1 kb=0..3 (As+Bs[W1]), then G2 kb=0..3 (Bs[W2]).
// Parity of every buffer = kb&1 for both phases (4 G1-units + 4 G2-units per c
// keep the global parity aligned). At each unit: barrier -> issue stage(next
// unit, opposite parity) -> compute(current unit). The Hc handoff needs no
// extra barriers: its previous readers (GEMM2 of c-1) retired >=4 barriers
// before the writes, and the next unit barrier publishes the writes to GEMM2(c).
// Hc: stride 256 + XOR swizzle (col ^ ((row&7)<<3)) -> 64 KB (fits 160 KB with
// double buffers), bank-even b128 reads, <=2-way u16 writes (quad parity in
// bank bit 4).
__global__ __launch_bounds__(512) void ff_fused(const ushort_t* __restrict__ yn,
                                                const ushort_t* __restrict__ W1b,
                                                const ushort_t* __restrict__ W2b,
                                                const float* __restrict__ bias1,
                                                const float* __restrict__ bias2,
                                                const ushort_t* __restrict__ xb,
                                                float* __restrict__ out) {
    __shared__ __attribute__((aligned(16))) ushort_t As[2][128 * 64];   // 32 KB
    __shared__ __attribute__((aligned(16))) ushort_t Bs[2][256 * 64];   // 64 KB
    __shared__ __attribute__((aligned(16))) ushort_t Hc[128 * 256];     // 64 KB

    const int t = threadIdx.x;
    const int m0 = blockIdx.x * 128;
    const int lane = t & 63;
    const int wave = t >> 6;
    const int wr = wave & 1, wc = wave >> 1;
    const int l16 = lane & 15, quad = lane >> 4;
    const int tr = t >> 3;
    const int csw = (((t & 7) ^ (tr & 7)) << 3);

    f32x4 acc2[4][4];
#pragma unroll
    for (int i = 0; i < 4; i++)
#pragma unroll
        for (int j = 0; j < 4; j++) acc2[i][j] = (f32x4)(0.0f);

    int c4[4];
#pragma unroll
    for (int j = 0; j < 4; j++) c4[j] = wc * 64 + j * 16 + l16;

    auto stage_g1 = [&](int cc, int kb) {
        ushort_t* a = As[kb & 1];
        ushort_t* b = Bs[kb & 1];
        const int kg = kb * 64;
#pragma unroll
        for (int p = 0; p < 2; ++p)
            gl2lds16(yn + (size_t)(m0 + p * 64 + tr) * 256 + kg + csw, a + p * 4096 + t * 8);
#pragma unroll
        for (int p = 0; p < 4; ++p)
            gl2lds16(W1b + (size_t)(cc * 256 + p * 64 + tr) * 256 + kg + csw, b + p * 4096 + t * 8);
    };
    auto stage_g2 = [&](int cc, int kb) {
        ushort_t* b = Bs[kb & 1];
#pragma unroll
        for (int p = 0; p < 4; ++p)
            gl2lds16(W2b + (size_t)(p * 64 + tr) * 2048 + cc * 256 + kb * 64 + csw, b + p * 4096 + t * 8);
    };

    stage_g1(0, 0);

#pragma unroll 1
    for (int c = 0; c < 8; ++c) {
        f32x4 acc1[4][4];
#pragma unroll
        for (int i = 0; i < 4; i++)
#pragma unroll
            for (int j = 0; j < 4; j++) acc1[i][j] = (f32x4)(0.0f);

        // ---- GEMM1: yn_tile[128x256] @ W1 rows [c*256, c*256+256)
#pragma unroll
        for (int kb = 0; kb < 4; ++kb) {
            __syncthreads();                       // drains this unit's stage
            if (kb < 3) stage_g1(c, kb + 1);       // prefetch next unit
            else        stage_g2(c, 0);            // G2 k0 has parity 0 (unit index 4)
            const ushort_t* a = As[kb & 1];
            const ushort_t* b = Bs[kb & 1];
#pragma unroll
            for (int kk = 0; kk < 2; ++kk) {
                const int ac = ((((kk << 2) | quad) ^ (l16 & 7)) << 3);
                bf16x8 af[4], bfv[4];
#pragma unroll
                for (int i = 0; i < 4; i++) af[i]  = *(const bf16x8*)&a[(wr * 64 + i * 16 + l16) * 64 + ac];
#pragma unroll
                for (int j = 0; j < 4; j++) bfv[j] = *(const bf16x8*)&b[(wc * 64 + j * 16 + l16) * 64 + ac];
#pragma unroll
                for (int i = 0; i < 4; i++)
#pragma unroll
                    for (int j = 0; j < 4; j++)
                        acc1[i][j] = __builtin_amdgcn_mfma_f32_16x16x32_bf16(af[i], bfv[j], acc1[i][j], 0, 0, 0);
            }
        }

        // ---- bias1 + relu -> Hc (bf16, XOR-swizzled, stride 256).
        // No barrier needed before: Hc readers of c-1 retired >=4 barriers ago.
        // Overlaps the stage_g2(c,0) DMA issued above.
#pragma unroll
        for (int j = 0; j < 4; j++) {
            const float bb = bias1[c * 256 + c4[j]];
#pragma unroll
            for (int i = 0; i < 4; i++) {
                const int rbase = wr * 64 + i * 16 + quad * 4;
#pragma unroll
                for (int r = 0; r < 4; r++) {
                    const int row = rbase + r;
                    float v = acc1[i][j][r] + bb;
                    v = v > 0.0f ? v : 0.0f;
                    Hc[row * 256 + (c4[j] ^ ((row & 7) << 3))] = f2b(v);
                }
            }
        }

        // ---- GEMM2: acc2 += Hc[128x256] @ W2 cols [c*256, c*256+256)
#pragma unroll
        for (int kb = 0; kb < 4; ++kb) {
            __syncthreads();                       // publishes Hc writes (kb=0) + drains stage
            if (kb < 3)      stage_g2(c, kb + 1);
            else if (c < 7)  stage_g1(c + 1, 0);   // next c's G1 k0, parity 0
            const ushort_t* b = Bs[kb & 1];
#pragma unroll
            for (int kk = 0; kk < 2; ++kk) {
                const int ank = kb * 64 + (((kk << 2) | quad) << 3);
                const int ah  = ank ^ ((l16 & 7) << 3);                   // Hc swizzle
                const int ac  = ((((kk << 2) | quad) ^ (l16 & 7)) << 3);  // Bs swizzle
                bf16x8 af[4], bfv[4];
#pragma unroll
                for (int i = 0; i < 4; i++) af[i]  = *(const bf16x8*)&Hc[(wr * 64 + i * 16 + l16) * 256 + ah];
#pragma unroll
                for (int j = 0; j < 4; j++) bfv[j] = *(const bf16x8*)&b[(wc * 64 + j * 16 + l16) * 64 + ac];
#pragma unroll
                for (int i = 0; i < 4; i++)
#pragma unroll
                    for (int j = 0; j < 4; j++)
                        acc2[i][j] = __builtin_amdgcn_mfma_f32_16x16x32_bf16(af[i], bfv[j], acc2[i][j], 0, 0, 0);
            }
        }
    }

    // ---- epilogue: + bias2 + xb residual -> out (f32)
#pragma unroll
    for (int j = 0; j < 4; j++) {
        const float b2 = bias2[c4[j]];
#pragma unroll
        for (int i = 0; i < 4; i++) {
            const int rbase = m0 + wr * 64 + i * 16 + quad * 4;
#pragma unroll
            for (int r = 0; r < 4; r++) {
                const size_t o = (size_t)(rbase + r) * 256 + c4[j];
                out[o] = acc2[i][j][r] + b2 + b2f(xb[o]);
            }
        }
    }
}

extern "C" void kernel_launch(void* const* d_in, const int* in_sizes, int n_in,
                              void* d_out, int out_size, void* d_ws, size_t ws_size,
                              hipStream_t stream) {
    const float* ent   = (const float*)d_in[0];
    const float* w_in  = (const float*)d_in[1];
    const float* w_out = (const float*)d_in[2];
    const float* W1    = (const float*)d_in[3];
    const float* bias1 = (const float*)d_in[4];
    const float* W2    = (const float*)d_in[5];
    const float* bias2 = (const float*)d_in[6];
    const float* g1    = (const float*)d_in[7];
    const float* be1   = (const float*)d_in[8];
    const float* g2    = (const float*)d_in[9];
    const float* be2   = (const float*)d_in[10];
    float* out = (float*)d_out;

    char* ws = (char*)d_ws;
    ushort_t* xn     = (ushort_t*)ws;
    ushort_t* yn     = (ushort_t*)(ws + 16777216);
    ushort_t* xb     = (ushort_t*)(ws + 2 * 16777216);
    ushort_t* bt_in  = (ushort_t*)(ws + 3 * 16777216);
    ushort_t* bt_out = bt_in + WELEM;
    ushort_t* W1b    = bt_out + WELEM;
    ushort_t* W2b    = W1b + WELEM;

    // 1) convert + repack weights to bf16
    convert_weights<<<dim3(768), dim3(256), 0, stream>>>(w_in, w_out, W1, W2,
                                                         bt_in, bt_out, W1b, W2b);
    // 2) LN1: ent -> xn (bf16)
    ln_fast<<<dim3(M_SZ / 4), dim3(256), 0, stream>>>(ent, g1, be1, xn);
    // 3) TT gemm + fused LN2: yn, xb
    tt_ln2<<<dim3(M_SZ / 128), dim3(512), 0, stream>>>(xn, bt_in, bt_out, g2, be2, ent, yn, xb);
    // 4) fused FF1+FF2: out = xb + relu(yn@W1^T+b1)@W2^T + b2
    ff_fused<<<dim3(M_SZ / 128), dim3(512), 0, stream>>>(yn, W1b, W2b, bias1, bias2, xb, out);
}

// Round 2
// 244.214 us; speedup vs baseline: 1.0640x; 1.0406x over previous
//
#include <hip/hip_runtime.h>
#include <hip/hip_bf16.h>

typedef unsigned short ushort_t;
typedef __attribute__((ext_vector_type(8))) short bf16x8;
typedef __attribute__((ext_vector_type(4))) float f32x4;

#define B_SZ 4096
#define N_SZ 8
#define D_SZ 256
#define FF_SZ 2048
#define M_SZ (B_SZ * N_SZ)   // 32768
#define WELEM (D_SZ * D_SZ * N_SZ)  // 524288

__device__ inline float b2f(ushort_t u) {
    union { unsigned int i; float f; } t; t.i = ((unsigned int)u) << 16; return t.f;
}
__device__ inline ushort_t f2b(float f) {
    union { unsigned int i; float f; } t; t.f = f;
    unsigned int i = t.i;
    unsigned int r = (i + 0x7fffu + ((i >> 16) & 1u)) >> 16;
    return (ushort_t)r;
}

// async global->LDS, 16B per lane; LDS dest must be wave-uniform base + lane*16
__device__ inline void gl2lds16(const ushort_t* g, ushort_t* l) {
    __builtin_amdgcn_global_load_lds((const __attribute__((address_space(1))) void*)g,
                                     (__attribute__((address_space(3))) void*)l, 16, 0, 0);
}

// ---------------- convert/repack all weights f32 -> bf16 (unchanged)
__global__ __launch_bounds__(256) void convert_weights(const float* __restrict__ w_in,
                                                       const float* __restrict__ w_out,
                                                       const float* __restrict__ W1,
                                                       const float* __restrict__ W2,
                                                       ushort_t* __restrict__ bt_in,
                                                       ushort_t* __restrict__ bt_out,
                                                       ushort_t* __restrict__ W1b,
                                                       ushort_t* __restrict__ W2b) {
    __shared__ float tile[64][65];
    const int bid = blockIdx.x;
    const int t = threadIdx.x;
    if (bid < 256) {
        const float* w = (bid < 128) ? w_in : w_out;
        ushort_t* bt = (bid < 128) ? bt_in : bt_out;
        const int id = bid & 127;
        const int d10 = (id >> 5) * 64;
        const int j0  = (id & 31) * 64;
#pragma unroll
        for (int it = 0; it < 16; ++it) {
            const int d1l = it * 4 + (t >> 6);
            const int jl = t & 63;
            tile[d1l][jl] = w[(size_t)(d10 + d1l) * 2048 + j0 + jl];
        }
        __syncthreads();
#pragma unroll
        for (int it = 0; it < 16; ++it) {
            const int jl = it * 4 + (t >> 6);
            const int d1l = t & 63;
            const int j = j0 + jl;
            bt[(size_t)(j >> 3) * 2048 + (j & 7) * 256 + d10 + d1l] = f2b(tile[d1l][jl]);
        }
    } else {
        const int id = bid - 256;
        const float* w = (id < 256) ? W1 : W2;
        ushort_t* o = (id < 256) ? W1b : W2b;
        const size_t base = (size_t)(id & 255) * 2048 + t * 8;
        const float4 a = *(const float4*)&w[base];
        const float4 b = *(const float4*)&w[base + 4];
        *(ushort4*)&o[base]     = make_ushort4(f2b(a.x), f2b(a.y), f2b(a.z), f2b(a.w));
        *(ushort4*)&o[base + 4] = make_ushort4(f2b(b.x), f2b(b.y), f2b(b.z), f2b(b.w));
    }
}

// ---------------- LN1: one WAVE per row of 256 (unchanged)
__global__ __launch_bounds__(256) void ln_fast(const float* __restrict__ xin,
                                               const float* __restrict__ gam,
                                               const float* __restrict__ bet,
                                               ushort_t* __restrict__ out) {
    const int wave = threadIdx.x >> 6;
    const int lane = threadIdx.x & 63;
    const size_t row = (size_t)blockIdx.x * 4 + wave;
    const float4 v = *(const float4*)&xin[row * 256 + lane * 4];
    float s = v.x + v.y + v.z + v.w;
    float q = v.x * v.x + v.y * v.y + v.z * v.z + v.w * v.w;
#pragma unroll
    for (int off = 1; off < 64; off <<= 1) {
        s += __shfl_xor(s, off, 64);
        q += __shfl_xor(q, off, 64);
    }
    const float mu = s * (1.0f / 256.0f);
    const float var = q * (1.0f / 256.0f) - mu * mu;
    const float rs = rsqrtf(var + 1e-5f);
    const float4 g = *(const float4*)&gam[lane * 4];
    const float4 b = *(const float4*)&bet[lane * 4];
    ushort4 o;
    o.x = f2b((v.x - mu) * rs * g.x + b.x);
    o.y = f2b((v.y - mu) * rs * g.y + b.y);
    o.z = f2b((v.z - mu) * rs * g.z + b.z);
    o.w = f2b((v.w - mu) * rs * g.w + b.w);
    *(ushort4*)&out[row * 256 + lane * 4] = o;
}

// ---------------- TT gemm + fused LN2: R11 occupancy restructure.
// R10 post-mortem: depth-1 prefetch moved MfmaUtil 26->27% only -> the stall is
// NOT the vmcnt drain; it is that the single resident block's 8 waves all park
// at every barrier with no co-resident block to fill the bubble (m97 evidence:
// 3 blocks/CU -> 37% MfmaUtil with the SAME naive 2-barrier unit).
// R11: 64-row tiles, 256 threads (4 waves, 1x4 grid, per-wave 64x64 preserved),
// single-buffered LDS (42 KB) -> grid 512 = 2 blocks/CU. Cross-block async
// replaces intra-block prefetch. Even/odd block swizzle keeps each XCD's L2 on
// a single Bt half.
__global__ __launch_bounds__(256, 2) void tt_ln2(const ushort_t* __restrict__ A,
                                                 const ushort_t* __restrict__ Bt0,
                                                 const ushort_t* __restrict__ Bt1,
                                                 const float* __restrict__ g2,
                                                 const float* __restrict__ be2,
                                                 const float* __restrict__ entf,
                                                 ushort_t* __restrict__ yn,
                                                 ushort_t* __restrict__ xb) {
    __shared__ __attribute__((aligned(16))) ushort_t As[64 * 64];    // 8 KB
    __shared__ __attribute__((aligned(16))) ushort_t Bs[256 * 64];   // 32 KB
    __shared__ float red_s[64 * 4];
    __shared__ float red_q[64 * 4];

    const int t = threadIdx.x;
    // launched-index -> logical-block swizzle: evens = first half (Bt0), odds =
    // second half (Bt1); round-robin XCD dispatch then gives each XCD one half.
    const int lb = ((blockIdx.x & 1) << 8) | (blockIdx.x >> 1);
    const int m0 = lb * 64;
    const int lane = t & 63;
    const int wc = t >> 6;                 // wave 0..3 -> output col group
    const int l16 = lane & 15, quad = lane >> 4;
    const int tr = t >> 3;                 // 0..31
    const int csw = (((t & 7) ^ (tr & 7)) << 3);

    const ushort_t* Bt = (m0 >= M_SZ / 2) ? Bt1 : Bt0;

    f32x4 acc[4][4];
#pragma unroll
    for (int i = 0; i < 4; i++)
#pragma unroll
        for (int j = 0; j < 4; j++) acc[i][j] = (f32x4)(0.0f);

#pragma unroll 1
    for (int kt = 0; kt < 32; ++kt) {
        const int kg = kt * 64;
        __syncthreads();   // previous unit's reads complete before overwrite
#pragma unroll
        for (int p = 0; p < 2; ++p) {
            const int mrow = m0 + p * 32 + tr;
            const int kcol = kg + csw;
            const int s = kcol >> 8;
            const ushort_t* gA = A + (size_t)((mrow & ~7) + (((mrow & 7) - s) & 7)) * 256 + (kcol & 255);
            gl2lds16(gA, As + p * 2048 + t * 8);
        }
#pragma unroll
        for (int p = 0; p < 8; ++p) {
            gl2lds16(Bt + (size_t)(p * 32 + tr) * 2048 + kg + csw, Bs + p * 2048 + t * 8);
        }
        __syncthreads();   // stage complete & visible

#pragma unroll
        for (int kk = 0; kk < 2; ++kk) {
            const int ac = ((((kk << 2) | quad) ^ (l16 & 7)) << 3);
            bf16x8 af[4], bfv[4];
#pragma unroll
            for (int i = 0; i < 4; i++) af[i]  = *(const bf16x8*)&As[(i * 16 + l16) * 64 + ac];
#pragma unroll
            for (int j = 0; j < 4; j++) bfv[j] = *(const bf16x8*)&Bs[(wc * 64 + j * 16 + l16) * 64 + ac];
#pragma unroll
            for (int i = 0; i < 4; i++)
#pragma unroll
                for (int j = 0; j < 4; j++)
                    acc[i][j] = __builtin_amdgcn_mfma_f32_16x16x32_bf16(af[i], bfv[j], acc[i][j], 0, 0, 0);
        }
    }

    int c[4];
#pragma unroll
    for (int j = 0; j < 4; j++) c[j] = wc * 64 + j * 16 + l16;
#pragma unroll
    for (int i = 0; i < 4; i++) {
#pragma unroll
        for (int r = 0; r < 4; r++) {
            const int rl = i * 16 + quad * 4 + r;
            const size_t grow = (size_t)(m0 + rl) * 256;
            float s = 0.0f, q = 0.0f;
#pragma unroll
            for (int j = 0; j < 4; j++) {
                float v = acc[i][j][r] + entf[grow + c[j]];
                acc[i][j][r] = v;
                s += v;
                q += v * v;
            }
#pragma unroll
            for (int off = 1; off < 16; off <<= 1) {
                s += __shfl_xor(s, off, 64);
                q += __shfl_xor(q, off, 64);
            }
            if (l16 == 0) { red_s[rl * 4 + wc] = s; red_q[rl * 4 + wc] = q; }
        }
    }
    __syncthreads();
#pragma unroll
    for (int i = 0; i < 4; i++) {
#pragma unroll
        for (int r = 0; r < 4; r++) {
            const int rl = i * 16 + quad * 4 + r;
            const size_t grow = (size_t)(m0 + rl) * 256;
            const float4 ss = *(const float4*)&red_s[rl * 4];
            const float4 qq = *(const float4*)&red_q[rl * 4];
            const float S = ss.x + ss.y + ss.z + ss.w;
            const float Q = qq.x + qq.y + qq.z + qq.w;
            const float mu = S * (1.0f / 256.0f);
            const float var = Q * (1.0f / 256.0f) - mu * mu;
            const float rs = rsqrtf(var + 1e-5f);
#pragma unroll
            for (int j = 0; j < 4; j++) {
                const float v = acc[i][j][r];
                yn[grow + c[j]] = f2b((v - mu) * rs * g2[c[j]] + be2[c[j]]);
                xb[grow + c[j]] = f2b(v);
            }
        }
    }
}

// ---------------- fused FF1+FF2: R11 occupancy restructure (same rationale).
// 64-row tile, 256 threads, single-buffered As(8K)+Bs(32K)+Hc(64x256=32K)=72 KB
// -> 2 blocks/CU. Every unit is the proven {sync; stage; sync; compute}
// bracket, so all LDS producer/consumer pairs stay barrier-separated:
//  - Hc writes happen after GEMM1 kb=3 compute; previous Hc readers (GEMM2 of
//    c-1) retired before G1(c) kb=0's first sync; next readers (GEMM2 of c)
//    start after G2 kb=0's syncs.
__global__ __launch_bounds__(256, 2) void ff_fused(const ushort_t* __restrict__ yn,
                                                   const ushort_t* __restrict__ W1b,
                                                   const ushort_t* __restrict__ W2b,
                                                   const float* __restrict__ bias1,
                                                   const float* __restrict__ bias2,
                                                   const ushort_t* __restrict__ xb,
                                                   float* __restrict__ out) {
    __shared__ __attribute__((aligned(16))) ushort_t As[64 * 64];    // 8 KB
    __shared__ __attribute__((aligned(16))) ushort_t Bs[256 * 64];   // 32 KB
    __shared__ __attribute__((aligned(16))) ushort_t Hc[64 * 256];   // 32 KB

    const int t = threadIdx.x;
    const int m0 = blockIdx.x * 64;
    const int lane = t & 63;
    const int wc = t >> 6;                 // wave 0..3 -> output col group
    const int l16 = lane & 15, quad = lane >> 4;
    const int tr = t >> 3;                 // 0..31
    const int csw = (((t & 7) ^ (tr & 7)) << 3);

    f32x4 acc2[4][4];
#pragma unroll
    for (int i = 0; i < 4; i++)
#pragma unroll
        for (int j = 0; j < 4; j++) acc2[i][j] = (f32x4)(0.0f);

    int c4[4];
#pragma unroll
    for (int j = 0; j < 4; j++) c4[j] = wc * 64 + j * 16 + l16;

#pragma unroll 1
    for (int c = 0; c < 8; ++c) {
        f32x4 acc1[4][4];
#pragma unroll
        for (int i = 0; i < 4; i++)
#pragma unroll
            for (int j = 0; j < 4; j++) acc1[i][j] = (f32x4)(0.0f);

        // ---- GEMM1: yn_tile[64x256] @ W1 rows [c*256, c*256+256)
#pragma unroll 1
        for (int kb = 0; kb < 4; ++kb) {
            const int kg = kb * 64;
            __syncthreads();   // prev reads done (kb=0: also GEMM2(c-1) Hc/Bs reads)
#pragma unroll
            for (int p = 0; p < 2; ++p)
                gl2lds16(yn + (size_t)(m0 + p * 32 + tr) * 256 + kg + csw, As + p * 2048 + t * 8);
#pragma unroll
            for (int p = 0; p < 8; ++p)
                gl2lds16(W1b + (size_t)(c * 256 + p * 32 + tr) * 256 + kg + csw, Bs + p * 2048 + t * 8);
            __syncthreads();   // stage complete & visible
#pragma unroll
            for (int kk = 0; kk < 2; ++kk) {
                const int ac = ((((kk << 2) | quad) ^ (l16 & 7)) << 3);
                bf16x8 af[4], bfv[4];
#pragma unroll
                for (int i = 0; i < 4; i++) af[i]  = *(const bf16x8*)&As[(i * 16 + l16) * 64 + ac];
#pragma unroll
                for (int j = 0; j < 4; j++) bfv[j] = *(const bf16x8*)&Bs[(wc * 64 + j * 16 + l16) * 64 + ac];
#pragma unroll
                for (int i = 0; i < 4; i++)
#pragma unroll
                    for (int j = 0; j < 4; j++)
                        acc1[i][j] = __builtin_amdgcn_mfma_f32_16x16x32_bf16(af[i], bfv[j], acc1[i][j], 0, 0, 0);
            }
        }

        // ---- bias1 + relu -> Hc (bf16, XOR-swizzled, stride 256).
        // Previous readers retired >= 2 barriers ago; published by G2 kb=0 syncs.
#pragma unroll
        for (int j = 0; j < 4; j++) {
            const float bb = bias1[c * 256 + c4[j]];
#pragma unroll
            for (int i = 0; i < 4; i++) {
                const int rbase = i * 16 + quad * 4;
#pragma unroll
                for (int r = 0; r < 4; r++) {
                    const int row = rbase + r;
                    float v = acc1[i][j][r] + bb;
                    v = v > 0.0f ? v : 0.0f;
                    Hc[row * 256 + (c4[j] ^ ((row & 7) << 3))] = f2b(v);
                }
            }
        }

        // ---- GEMM2: acc2 += Hc[64x256] @ W2 cols [c*256, c*256+256)
#pragma unroll 1
        for (int kb = 0; kb < 4; ++kb) {
            __syncthreads();   // kb=0: publishes Hc + drains G1 Bs reads; kb>0: drains Bs reads
#pragma unroll
            for (int p = 0; p < 8; ++p)
                gl2lds16(W2b + (size_t)(p * 32 + tr) * 2048 + c * 256 + kb * 64 + csw, Bs + p * 2048 + t * 8);
            __syncthreads();   // stage complete & visible
#pragma unroll
            for (int kk = 0; kk < 2; ++kk) {
                const int ank = kb * 64 + (((kk << 2) | quad) << 3);
                const int ah  = ank ^ ((l16 & 7) << 3);                   // Hc swizzle
                const int ac  = ((((kk << 2) | quad) ^ (l16 & 7)) << 3);  // Bs swizzle
                bf16x8 af[4], bfv[4];
#pragma unroll
                for (int i = 0; i < 4; i++) af[i]  = *(const bf16x8*)&Hc[(i * 16 + l16) * 256 + ah];
#pragma unroll
                for (int j = 0; j < 4; j++) bfv[j] = *(const bf16x8*)&Bs[(wc * 64 + j * 16 + l16) * 64 + ac];
#pragma unroll
                for (int i = 0; i < 4; i++)
#pragma unroll
                    for (int j = 0; j < 4; j++)
                        acc2[i][j] = __builtin_amdgcn_mfma_f32_16x16x32_bf16(af[i], bfv[j], acc2[i][j], 0, 0, 0);
            }
        }
    }

    // ---- epilogue: + bias2 + xb residual -> out (f32)
#pragma unroll
    for (int j = 0; j < 4; j++) {
        const float b2 = bias2[c4[j]];
#pragma unroll
        for (int i = 0; i < 4; i++) {
            const int rbase = m0 + i * 16 + quad * 4;
#pragma unroll
            for (int r = 0; r < 4; r++) {
                const size_t o = (size_t)(rbase + r) * 256 + c4[j];
                out[o] = acc2[i][j][r] + b2 + b2f(xb[o]);
            }
        }
    }
}

extern "C" void kernel_launch(void* const* d_in, const int* in_sizes, int n_in,
                              void* d_out, int out_size, void* d_ws, size_t ws_size,
                              hipStream_t stream) {
    const float* ent   = (const float*)d_in[0];
    const float* w_in  = (const float*)d_in[1];
    const float* w_out = (const float*)d_in[2];
    const float* W1    = (const float*)d_in[3];
    const float* bias1 = (const float*)d_in[4];
    const float* W2    = (const float*)d_in[5];
    const float* bias2 = (const float*)d_in[6];
    const float* g1    = (const float*)d_in[7];
    const float* be1   = (const float*)d_in[8];
    const float* g2    = (const float*)d_in[9];
    const float* be2   = (const float*)d_in[10];
    float* out = (float*)d_out;

    char* ws = (char*)d_ws;
    ushort_t* xn     = (ushort_t*)ws;
    ushort_t* yn     = (ushort_t*)(ws + 16777216);
    ushort_t* xb     = (ushort_t*)(ws + 2 * 16777216);
    ushort_t* bt_in  = (ushort_t*)(ws + 3 * 16777216);
    ushort_t* bt_out = bt_in + WELEM;
    ushort_t* W1b    = bt_out + WELEM;
    ushort_t* W2b    = W1b + WELEM;

    // 1) convert + repack weights to bf16
    convert_weights<<<dim3(768), dim3(256), 0, stream>>>(w_in, w_out, W1, W2,
                                                         bt_in, bt_out, W1b, W2b);
    // 2) LN1: ent -> xn (bf16)
    ln_fast<<<dim3(M_SZ / 4), dim3(256), 0, stream>>>(ent, g1, be1, xn);
    // 3) TT gemm + fused LN2: yn, xb  (64-row tiles, 2 blocks/CU)
    tt_ln2<<<dim3(M_SZ / 64), dim3(256), 0, stream>>>(xn, bt_in, bt_out, g2, be2, ent, yn, xb);
    // 4) fused FF1+FF2: out = xb + relu(yn@W1^T+b1)@W2^T + b2  (64-row tiles, 2 blocks/CU)
    ff_fused<<<dim3(M_SZ / 64), dim3(256), 0, stream>>>(yn, W1b, W2b, bias1, bias2, xb, out);
}